// Round 13
// baseline (176.725 us; speedup 1.0000x reference)
//
#include <hip/hip_runtime.h>
#include <math.h>

// B=2048, S=8, D=1280, K=1 rank-1 common-mode removal.
// R13: UNFUSE. Five fused variants (R9-R12) all land in a 72-88us basin:
// per-block serial chains (gram->reduce->eigen->apply) + eigen redundancy
// (2048 x 4k inst = ~7us VALU on critical path) + barriers coupling memory
// and compute phases. Decompose into 3 barrier-free kernels, each at its
// own optimal shape, 600KB workspace glue:
//  K1 gram : 1 wave/batch streamed fp32 (no spill, 8 waves/CU), butterfly,
//            lane0 stores 52 floats transposed [field][B] (coalesced in K2).
//  K2 eigen: THREAD-per-batch (32 waves) -- proven chain, zero redundancy,
//            coalesced loads/stores via transposed layouts.
//  K3 apply: R7's 320-thr/block streamer verbatim (40 waves/CU, scalar-load
//            coefs, float4 in/out, 166MB ~ 30us).

#define SV 8
#define DV 1280
#define D4 320             // float4 per row
#define BSTRIDE (SV*DV)    // 10240 floats per batch

__device__ __forceinline__ float wsum(float v) {
    v += __shfl_xor(v, 32);
    v += __shfl_xor(v, 16);
    v += __shfl_xor(v, 8);
    v += __shfl_xor(v, 4);
    v += __shfl_xor(v, 2);
    v += __shfl_xor(v, 1);
    return v;
}

// constant-index upper-triangle accessors (i,k compile-time constants)
#define GU(i,k) ((i) <= (k) ? G[i][k] : G[k][i])
#define AU(i,k) ((i) <= (k) ? A[i][k] : A[k][i])

// ---------------- K1: streamed gram, 1 wave per batch ----------------
__global__ __launch_bounds__(64)
void cmr_gram(const float* __restrict__ feat, float* __restrict__ gws, int Bn)
{
    const int lane = threadIdx.x;
    const int b    = blockIdx.x;

    const float* __restrict__ fb = feat + (size_t)b * BSTRIDE + lane * 2;

    float G[8][8];                          // only j>=i written
    float S[8];
#pragma unroll
    for (int i = 0; i < 8; ++i) {
        S[i] = 0.f;
#pragma unroll
        for (int j = i; j < 8; ++j) G[i][j] = 0.f;
    }
#pragma unroll
    for (int c = 0; c < 10; ++c) {          // 10 x 128-float chunks
        float2 x[8];
#pragma unroll
        for (int s = 0; s < 8; ++s)
            x[s] = *(const float2*)(fb + (size_t)s * DV + c * 128);
#pragma unroll
        for (int i = 0; i < 8; ++i) {
            S[i] += x[i].x + x[i].y;
#pragma unroll
            for (int j = i; j < 8; ++j)
                G[i][j] = fmaf(x[i].x, x[j].x,
                          fmaf(x[i].y, x[j].y, G[i][j]));
        }
    }
#pragma unroll
    for (int i = 0; i < 8; ++i) {
        S[i] = wsum(S[i]);
#pragma unroll
        for (int j = i; j < 8; ++j) G[i][j] = wsum(G[i][j]);
    }
    if (lane == 0) {                        // transposed: gws[f*Bn + b]
        int p = 0;
#pragma unroll
        for (int i = 0; i < 8; ++i)
#pragma unroll
            for (int j = i; j < 8; ++j) { gws[(size_t)p * Bn + b] = G[i][j]; ++p; }
#pragma unroll
        for (int i = 0; i < 8; ++i) gws[(size_t)(44 + i) * Bn + b] = S[i];
    }
}

// ---------------- K2: eigen, 1 THREAD per batch ----------------
__global__ __launch_bounds__(64, 1)
void cmr_eigen(const float* __restrict__ gws,
               const float* __restrict__ kp,
               const float* __restrict__ cmr_gate,
               float* __restrict__ cf,
               float* __restrict__ out, int Bn)
{
    const int b = blockIdx.x * 64 + threadIdx.x;

    float G[8][8], S[8], mu[8], sig[8], rsig[8];
    {
        int p = 0;
#pragma unroll
        for (int i = 0; i < 8; ++i)
#pragma unroll
            for (int j = i; j < 8; ++j) { G[i][j] = gws[(size_t)p * Bn + b]; ++p; }
#pragma unroll
        for (int i = 0; i < 8; ++i) S[i] = gws[(size_t)(44 + i) * Bn + b];
    }
    const float invD = 1.f / (float)DV;
#pragma unroll
    for (int i = 0; i < 8; ++i) {
        mu[i] = S[i] * invD;
        const float var = fmaxf(G[i][i] * invD - mu[i] * mu[i], 0.f);
        sig[i]  = sqrtf(var) + 1e-8f;       // numpy std(ddof=0)+1e-8
        rsig[i] = 1.f / sig[i];
    }
#pragma unroll
    for (int i = 0; i < 8; ++i)
#pragma unroll
        for (int j = i; j < 8; ++j)
            G[i][j] = (G[i][j] - (float)DV * mu[i] * mu[j]) * rsig[i] * rsig[j];

    float tr = 0.f;
#pragma unroll
    for (int i = 0; i < 8; ++i) tr += G[i][i];

    float A[8][8];
    {
        const float rt = 1.f / fmaxf(tr, 1e-30f);
#pragma unroll
        for (int i = 0; i < 8; ++i)
#pragma unroll
            for (int j = i; j < 8; ++j) A[i][j] = G[i][j] * rt;
    }
#pragma unroll
    for (int t = 0; t < 12; ++t) {
        float Bm[8][8];
        float trB = 0.f;
#pragma unroll
        for (int i = 0; i < 8; ++i)
#pragma unroll
            for (int j = i; j < 8; ++j) {
                float acc = 0.f;
#pragma unroll
                for (int k = 0; k < 8; ++k)
                    acc = fmaf(AU(i, k), AU(j, k), acc);   // A symmetric
                Bm[i][j] = acc;
                if (i == j) trB += acc;
            }
        const float rt = 1.f / fmaxf(trB, 1e-30f);
#pragma unroll
        for (int i = 0; i < 8; ++i)
#pragma unroll
            for (int j = i; j < 8; ++j) A[i][j] = Bm[i][j] * rt;
    }
    int bj = 0; float best = A[0][0];
#pragma unroll
    for (int k = 1; k < 8; ++k)
        if (A[k][k] > best) { best = A[k][k]; bj = k; }
    float u[8];
#pragma unroll
    for (int i = 0; i < 8; ++i) {
        float v = AU(i, 0);
#pragma unroll
        for (int k = 1; k < 8; ++k) v = (bj == k) ? AU(i, k) : v;
        u[i] = v;
    }
    {
        float nn = 0.f;
#pragma unroll
        for (int i = 0; i < 8; ++i) nn = fmaf(u[i], u[i], nn);
        const float r = rsqrtf(fmaxf(nn, 1e-30f));
#pragma unroll
        for (int i = 0; i < 8; ++i) u[i] *= r;
    }
#pragma unroll
    for (int it = 0; it < 2; ++it) {
        float y[8]; float ny = 0.f;
#pragma unroll
        for (int i = 0; i < 8; ++i) {
            float acc = 0.f;
#pragma unroll
            for (int k = 0; k < 8; ++k) acc = fmaf(GU(i, k), u[k], acc);
            y[i] = acc; ny = fmaf(acc, acc, ny);
        }
        const float r = rsqrtf(fmaxf(ny, 1e-30f));
#pragma unroll
        for (int i = 0; i < 8; ++i) u[i] = y[i] * r;
    }
    float lam = 0.f;
#pragma unroll
    for (int i = 0; i < 8; ++i) {
        float acc = 0.f;
#pragma unroll
        for (int k = 0; k < 8; ++k) acc = fmaf(GU(i, k), u[k], acc);
        lam = fmaf(u[i], acc, lam);
    }
    const float pc1 = lam / (tr + 1e-8f);

    const float gate = 1.f / (1.f + expf(-cmr_gate[0]));
    const float kpg  = (kp[b] >= 5.0f) ? 1.5f : 1.0f;
    const float Gt   = gate * kpg;

    float bc = 0.f;
#pragma unroll
    for (int i = 0; i < 8; ++i) bc = fmaf(u[i] * rsig[i], mu[i], bc);

#pragma unroll
    for (int i = 0; i < 8; ++i) {           // transposed: cf[k*Bn + b]
        cf[(size_t)i * Bn + b]       = u[i] * rsig[i];     // a_i
        cf[(size_t)(8 + i) * Bn + b] = Gt * sig[i] * u[i]; // coef_i
    }
    cf[(size_t)16 * Bn + b] = bc;
    out[(size_t)Bn * BSTRIDE + b] = pc1;
    out[(size_t)Bn * BSTRIDE + Bn + b] =
        (pc1 >= 0.6f ? 1.f : 0.f) + (pc1 >= 0.8f ? 1.f : 0.f);
}

// ---------------- K3: streaming apply (R7 structure) ----------------
__global__ __launch_bounds__(320)
void cmr_apply(const float* __restrict__ feat,
               const float* __restrict__ cf,
               float* __restrict__ out, int Bn)
{
    const int tid  = threadIdx.x;
    const int lane = tid & 63;
    const int wq   = tid >> 6;
    const int b    = blockIdx.x;

    float a[8], c[8];                       // uniform -> scalar loads
#pragma unroll
    for (int s = 0; s < 8; ++s) {
        a[s] = cf[(size_t)s * Bn + b];
        c[s] = cf[(size_t)(8 + s) * Bn + b];
    }
    const float bc = cf[(size_t)16 * Bn + b];

    const float4* __restrict__ f4 = (const float4*)(feat + (size_t)b * BSTRIDE);
    float4* __restrict__ o4 = (float4*)(out + (size_t)b * BSTRIDE);
    const int d4 = wq * 64 + lane;

    float4 f[8];
#pragma unroll
    for (int s = 0; s < 8; ++s) f[s] = f4[s * D4 + d4];

    float4 p = make_float4(-bc, -bc, -bc, -bc);
#pragma unroll
    for (int s = 0; s < 8; ++s) {
        p.x = fmaf(a[s], f[s].x, p.x);
        p.y = fmaf(a[s], f[s].y, p.y);
        p.z = fmaf(a[s], f[s].z, p.z);
        p.w = fmaf(a[s], f[s].w, p.w);
    }
#pragma unroll
    for (int s = 0; s < 8; ++s) {
        float4 o;
        o.x = fmaf(-c[s], p.x, f[s].x);
        o.y = fmaf(-c[s], p.y, f[s].y);
        o.z = fmaf(-c[s], p.z, f[s].z);
        o.w = fmaf(-c[s], p.w, f[s].w);
        o4[s * D4 + d4] = o;
    }
}

extern "C" void kernel_launch(void* const* d_in, const int* in_sizes, int n_in,
                              void* d_out, int out_size, void* d_ws, size_t ws_size,
                              hipStream_t stream) {
    const float* feat = (const float*)d_in[0];
    const float* kp   = (const float*)d_in[1];
    const float* gate = (const float*)d_in[2];
    float* out = (float*)d_out;
    const int Bn = in_sizes[0] / BSTRIDE;        // 2048

    float* gws = (float*)d_ws;                   // 52*Bn floats
    float* cf  = gws + (size_t)52 * Bn;          // 17*Bn floats

    cmr_gram <<<Bn,      64,  0, stream>>>(feat, gws, Bn);
    cmr_eigen<<<Bn / 64, 64,  0, stream>>>(gws, kp, gate, cf, out, Bn);
    cmr_apply<<<Bn,      320, 0, stream>>>(feat, cf, out, Bn);
}